// Round 8
// baseline (210.197 us; speedup 1.0000x reference)
//
#include <hip/hip_runtime.h>
#include <stdint.h>

typedef __bf16 bf8 __attribute__((ext_vector_type(8)));
typedef float f4 __attribute__((ext_vector_type(4)));
typedef float f16v __attribute__((ext_vector_type(16)));
typedef unsigned short us8 __attribute__((ext_vector_type(8)));
typedef unsigned short us4 __attribute__((ext_vector_type(4)));

#define MFMA16(a, b, c) __builtin_amdgcn_mfma_f32_16x16x32_bf16(a, b, c, 0, 0, 0)
#define MFMA32(a, b, c) __builtin_amdgcn_mfma_f32_32x32x16_bf16(a, b, c, 0, 0, 0)

__device__ __forceinline__ unsigned short f2b(float f) {
  union { float f; unsigned u; } x; x.f = f;
  unsigned u = x.u;
  u += 0x7fffu + ((u >> 16) & 1u);   // RNE
  return (unsigned short)(u >> 16);
}

// pack bf16(a) low, bf16(b) high — single instr (RNE)
__device__ __forceinline__ unsigned cvtpk(float a, float b) {
  unsigned r;
  asm("v_cvt_pk_bf16_f32 %0, %1, %2" : "=v"(r) : "v"(a), "v"(b));
  return r;
}

// v_permlane32_swap_b32: a' = {a.lo32lanes, b.lo32lanes}, b' = {a.hi, b.hi}
__device__ __forceinline__ void plswap(unsigned &a, unsigned &b) {
  asm("v_permlane32_swap_b32 %0, %1" : "+v"(a), "+v"(b));
}

// async global->LDS 16B per lane; lds dest = wave-uniform base + lane*16
__device__ __forceinline__ void gload16(const void* g, void* l) {
  __builtin_amdgcn_global_load_lds(
      (const __attribute__((address_space(1))) void*)g,
      (__attribute__((address_space(3))) void*)l, 16, 0, 0);
}

// ---- fused: fp32 W[k][n] -> bf16 Wt[n][k] (z<4) + hidden fp32->bf16 (z==4) ----
// Also zeroes the flash work-queue counter (runs before flash every call).
__global__ __launch_bounds__(256) void prep_kernel(
    const float* __restrict__ W0, const float* __restrict__ W1,
    const float* __restrict__ W2, const float* __restrict__ W3,
    unsigned short* __restrict__ T0, unsigned short* __restrict__ T1,
    unsigned short* __restrict__ T2, unsigned short* __restrict__ T3,
    const float* __restrict__ hid, unsigned short* __restrict__ hb,
    int* __restrict__ cnt) {
  if (blockIdx.z == 4) {
    int bi = blockIdx.x + 32 * blockIdx.y;        // 0..1023
    if (bi == 0 && threadIdx.x == 0) *cnt = 0;
#pragma unroll
    for (int k = 0; k < 4; ++k) {
      int i = bi * 1024 + k * 256 + threadIdx.x;
      float4 v = ((const float4*)hid)[i];
      us4 r = { f2b(v.x), f2b(v.y), f2b(v.z), f2b(v.w) };
      *(us4*)(hb + (size_t)i * 4) = r;
    }
    return;
  }
  const float* W; unsigned short* Wt;
  if (blockIdx.z == 0)      { W = W0; Wt = T0; }
  else if (blockIdx.z == 1) { W = W1; Wt = T1; }
  else if (blockIdx.z == 2) { W = W2; Wt = T2; }
  else                      { W = W3; Wt = T3; }
  __shared__ float tile[32][33];
  int tx = threadIdx.x & 31, ty = threadIdx.x >> 5;   // 32 x 8
  int kb = blockIdx.x * 32, nb = blockIdx.y * 32;
#pragma unroll
  for (int j = 0; j < 32; j += 8)
    tile[ty + j][tx] = W[(size_t)(kb + ty + j) * 1024 + nb + tx];
  __syncthreads();
#pragma unroll
  for (int j = 0; j < 32; j += 8)
    Wt[(size_t)(nb + ty + j) * 1024 + kb + tx] = f2b(tile[tx][ty + j]);
}

// ---------------- QKV projection GEMM (+ fused RoPE for Q,K) ----------------
// BK=64 (halves barrier/vmcnt-drain count vs BK=32). Chunk XOR swizzle on both
// sides (pre-swizzled global source + swizzled read slot) keeps ds_read_b128 at
// the 8-lanes/bank-group BW floor. Accumulation order == BK=32 (bit-identical).
// Q: bf16 (bh,s,d) row-major, pre-scaled by 0.125*log2(e).
// K: bf16 FRAGMENT-READY; V: bf16 FRAGMENT-READY (see flash kernel).
__global__ __launch_bounds__(256) void gemm_qkv_kernel(
    const unsigned short* __restrict__ X,
    const unsigned short* __restrict__ Wqt, const unsigned short* __restrict__ Wkt,
    const unsigned short* __restrict__ Wvt,
    const float* __restrict__ bq, const float* __restrict__ bk,
    const float* __restrict__ bv,
    unsigned short* __restrict__ Qo, unsigned short* __restrict__ Ko,
    unsigned short* __restrict__ Vo) {
  const unsigned short* Wt; const float* bias; unsigned short* out;
  if (blockIdx.z == 0)      { Wt = Wqt; bias = bq; out = Qo; }
  else if (blockIdx.z == 1) { Wt = Wkt; bias = bk; out = Ko; }
  else                      { Wt = Wvt; bias = bv; out = Vo; }

  __shared__ unsigned short As[128 * 64];
  __shared__ unsigned short Bs[128 * 64];
  const int t = threadIdx.x;
  const int wave = t >> 6, lane = t & 63, quad = lane >> 4, l16 = lane & 15;
  const int wm = (wave >> 1) * 64, wn = (wave & 1) * 64;
  const int m0 = blockIdx.y * 128, n0 = blockIdx.x * 128;

  f4 acc[4][4];
#pragma unroll
  for (int mi = 0; mi < 4; ++mi)
#pragma unroll
    for (int ni = 0; ni < 4; ++ni) acc[mi][ni] = (f4)0.0f;

  for (int k0 = 0; k0 < 1024; k0 += 64) {
    __syncthreads();
#pragma unroll
    for (int it = 0; it < 4; ++it) {
      int chunk = it * 256 + wave * 64 + lane;      // 0..1023 (128 rows x 8 chunks)
      int row = chunk >> 3, cc = chunk & 7;
      int csw = cc ^ (row & 7);                     // pre-swizzled global source
      gload16(&X[(size_t)(m0 + row) * 1024 + k0 + csw * 8],
              &As[(size_t)(it * 256 + wave * 64) * 8]);
      gload16(&Wt[(size_t)(n0 + row) * 1024 + k0 + csw * 8],
              &Bs[(size_t)(it * 256 + wave * 64) * 8]);
    }
    __syncthreads();
#pragma unroll
    for (int kk = 0; kk < 2; ++kk) {
      const int sw = (kk * 4 + quad) ^ (l16 & 7);   // swizzled read slot
      bf8 a[4], b[4];
#pragma unroll
      for (int mi = 0; mi < 4; ++mi)
        a[mi] = *(const bf8*)&As[(wm + mi * 16 + l16) * 64 + sw * 8];
#pragma unroll
      for (int ni = 0; ni < 4; ++ni)
        b[ni] = *(const bf8*)&Bs[(wn + ni * 16 + l16) * 64 + sw * 8];
#pragma unroll
      for (int mi = 0; mi < 4; ++mi)
#pragma unroll
        for (int ni = 0; ni < 4; ++ni)
          acc[mi][ni] = MFMA16(a[mi], b[ni], acc[mi][ni]);
    }
  }

  float biasv[4];
#pragma unroll
  for (int ni = 0; ni < 4; ++ni) biasv[ni] = bias[n0 + wn + ni * 16 + l16];

  if (blockIdx.z < 2) {
    const float kr = 13.287712379549449f / 32.0f;   // log2(10000)/32
    const float f0 = exp2f(-(float)l16 * kr);
    const float f1 = exp2f(-(float)(l16 + 16) * kr);
    const float qs = (blockIdx.z == 0) ? 0.18033688011112042f : 1.0f;
#pragma unroll
    for (int mi = 0; mi < 4; ++mi) {
#pragma unroll
      for (int r = 0; r < 4; ++r) {
        int m = m0 + wm + mi * 16 + quad * 4 + r;
        float s = (float)(m & 2047);
        float s0, c0, s1, c1;
        __sincosf(s * f0, &s0, &c0);
        __sincosf(s * f1, &s1, &c1);
        float v0 = acc[mi][0][r] + biasv[0];
        float v1 = acc[mi][1][r] + biasv[1];
        acc[mi][0][r] = (v0 * c0 - v1 * s0) * qs;
        acc[mi][1][r] = (v1 * c1 - v0 * s1) * qs;
        acc[mi][2][r] = (acc[mi][2][r] + biasv[2]) * qs;
        acc[mi][3][r] = (acc[mi][3][r] + biasv[3]) * qs;
      }
    }
    if (blockIdx.z == 0) {
      // Q: row-major (bh, s, d)
#pragma unroll
      for (int ni = 0; ni < 4; ++ni) {
        int n = n0 + wn + ni * 16 + l16;
        int h = n >> 6, d = n & 63;
#pragma unroll
        for (int mi = 0; mi < 4; ++mi) {
#pragma unroll
          for (int r = 0; r < 4; ++r) {
            int m = m0 + wm + mi * 16 + quad * 4 + r;
            int b_ = m >> 11, s = m & 2047;
            out[(size_t)(((b_ << 4) | h) * 2048 + s) * 64 + d] = f2b(acc[mi][ni][r]);
          }
        }
      }
    } else {
      // K: fragment-ready layout
#pragma unroll
      for (int ni = 0; ni < 4; ++ni) {
        int n = n0 + wn + ni * 16 + l16;
        int h = n >> 6, d = n & 63;
        int cpart = (d >> 4) * 512 + ((d >> 3) & 1) * 256 + (d & 7);
#pragma unroll
        for (int mi = 0; mi < 4; ++mi) {
#pragma unroll
          for (int r = 0; r < 4; ++r) {
            int m = m0 + wm + mi * 16 + quad * 4 + r;
            int b_ = m >> 11, s = m & 2047;
            size_t off = (size_t)((b_ << 4) | h) * 131072
                       + (size_t)(s >> 5) * 2048 + (s & 31) * 8 + cpart;
            out[off] = f2b(acc[mi][ni][r]);
          }
        }
      }
    }
  } else {
    // V: fragment-ready layout (us4 = 4 consecutive s at fixed d)
#pragma unroll
    for (int ni = 0; ni < 4; ++ni) {
      int n = n0 + wn + ni * 16 + l16;
      int h = n >> 6, d = n & 63;
      int dpart = ((d >> 5) & 1) * 2048 + (d & 31) * 8;
#pragma unroll
      for (int mi = 0; mi < 4; ++mi) {
        int m = m0 + wm + mi * 16 + quad * 4;
        int b_ = m >> 11, s = m & 2047;
        us4 w = { f2b(acc[mi][ni][0] + biasv[ni]), f2b(acc[mi][ni][1] + biasv[ni]),
                  f2b(acc[mi][ni][2] + biasv[ni]), f2b(acc[mi][ni][3] + biasv[ni]) };
        size_t off = (size_t)((b_ << 4) | h) * 131072
                   + (size_t)(s >> 6) * 4096 + ((s >> 4) & 3) * 512
                   + ((s >> 3) & 1) * 256 + dpart + (s & 7);
        *(us4*)&out[off] = w;
      }
    }
  }
}

// ------------- causal flash attention: PERSISTENT blocks + dynamic LPT queue ----
// Round-8: OccupancyPercent ~9.3% (time-avg ~3 waves/CU vs 12 resident) said the
// CUs are DRAINED most of the kernel: only 1024 blocks, short ones retire early,
// the long waves finish alone. Fix: 768 persistent blocks (exactly 3/CU at VGPR
// ~136) pull items from a global atomic queue, heaviest-first (qt = 31 - s>>5).
// Blocks never retire until the queue drains; tail = 1-step items. Inner step
// body is R7's (proven 51.8us): V issued after QK^T, split softmax, cvt_pk.
__global__ __launch_bounds__(256) void flash_attn_kernel(
    const unsigned short* __restrict__ Q, const unsigned short* __restrict__ K,
    const unsigned short* __restrict__ Vt, unsigned short* __restrict__ ctx,
    int* __restrict__ cnt) {
  __shared__ __align__(16) float osh[2][64][36];   // stride 36: 16B-aligned rows
  __shared__ float lsh[2][64];
  __shared__ int sItem;
  const int t = threadIdx.x;
  const int lane = t & 63;
  const int wave = t >> 6, l32 = lane & 31, hl = lane >> 5;
  const int sub = wave >> 1;                     // q-subtile within 64-row tile
  const int kh  = wave & 1;                      // k-half

  for (;;) {
    if (t == 0) sItem = atomicAdd(cnt, 1);
    __syncthreads();                             // broadcast + protects osh reuse
    const int s = sItem;
    if (s >= 1024) return;

    const int bh = s & 31;
    const int qt = 31 - (s >> 5);                // LPT: heaviest first
    const int b = bh >> 4, h = bh & 15;

    const unsigned short* Qh = Q + (size_t)bh * 131072;
    const unsigned short* Kh = K + (size_t)bh * 131072;
    const unsigned short* Vh = Vt + (size_t)bh * 131072;

    const int wrow0 = qt * 64 + sub * 32;
    const int q = wrow0 + l32;                   // lane's q-column

    // Q as B-operand: B[k=d][n=q]; chunk c covers d = c*16 + hl*8 + j
    bf8 qb[4];
#pragma unroll
    for (int c = 0; c < 4; ++c)
      qb[c] = *(const bf8*)&Qh[(size_t)q * 64 + c * 16 + hl * 8];

    f16v o0 = (f16v)0.0f, o1 = (f16v)0.0f;       // O^T: d 0..31, 32..63
    float sum = 0.0f;                            // per-lane partial l

    bf8 kfA[2][4], kfB[2][4];
    const int nk = qt + 1;                       // total 64-wide k-steps
    const int kb = kh ? (nk >> 1) : 0;           // this wave's half
    const int ke = kh ? nk : (nk >> 1);

    // fragment-ready K: chunk off (ushorts) = kt*4096 + mt*2048 + c*512 + lane*8
    auto loadK = [&](bf8 (&kf)[2][4], int kt) {
      const unsigned short* p = Kh + (size_t)kt * 4096 + lane * 8;
#pragma unroll
      for (int mt = 0; mt < 2; ++mt)
#pragma unroll
        for (int c = 0; c < 4; ++c)
          kf[mt][c] = *(const bf8*)&p[mt * 2048 + c * 512];
    };

    auto step = [&](int kt, bf8 (&kf)[2][4]) {
      const int k0 = kt * 64;

      // S^T = K Q^T : two 32x32 tiles over kk (reg gg*4+i <-> kk=gg*8+hl*4+i)
      f16v s0 = (f16v)0.0f, s1 = (f16v)0.0f;
#pragma unroll
      for (int c = 0; c < 4; ++c) {
        s0 = MFMA32(kf[0][c], qb[c], s0);
        s1 = MFMA32(kf[1][c], qb[c], s1);
      }
      __builtin_amdgcn_sched_barrier(0);   // pin V loads BELOW QK^T (VGPR peak)

      // fragment-ready V; issued here, latency covered by softmax-s0 below.
      const unsigned short* pv = Vh + (size_t)kt * 4096 + lane * 8;
      bf8 vf[2][4];
#pragma unroll
      for (int c = 0; c < 4; ++c)
#pragma unroll
        for (int dt = 0; dt < 2; ++dt)
          vf[dt][c] = *(const bf8*)&pv[dt * 2048 + c * 512];

      // causal mask: provably only the last tile of the full range
      if (kt == nk - 1) {
#pragma unroll
        for (int gg = 0; gg < 4; ++gg)
#pragma unroll
          for (int i = 0; i < 4; ++i) {
            int kk = k0 + gg * 8 + hl * 4 + i;
            if (kk > q) s0[gg * 4 + i] = -3e38f;
            if (kk + 32 > q) s1[gg * 4 + i] = -3e38f;
          }
      }

      // ---- first half: s0 -> fragments c=0,1 -> PV ----
      {
        uint2 pd2[4];
#pragma unroll
        for (int gg = 0; gg < 4; ++gg) {
          float p0 = exp2f(s0[gg * 4 + 0]), p1 = exp2f(s0[gg * 4 + 1]);
          float p2 = exp2f(s0[gg * 4 + 2]), p3 = exp2f(s0[gg * 4 + 3]);
          sum += (p0 + p1) + (p2 + p3);
          pd2[gg].x = cvtpk(p0, p1); pd2[gg].y = cvtpk(p2, p3);
        }
#pragma unroll
        for (int c = 0; c < 2; ++c) {
          unsigned ax = pd2[2 * c].x, bx = pd2[2 * c + 1].x;
          unsigned ay = pd2[2 * c].y, by = pd2[2 * c + 1].y;
          plswap(ax, bx);
          plswap(ay, by);
          union { uint4 u; bf8 v; } pv2; pv2.u = (uint4){ax, ay, bx, by};
          o0 = MFMA32(vf[0][c], pv2.v, o0);
          o1 = MFMA32(vf[1][c], pv2.v, o1);
        }
      }
      // ---- second half: s1 -> fragments c=2,3 -> PV ----
      {
        uint2 pd2[4];
#pragma unroll
        for (int gg = 0; gg < 4; ++gg) {
          float r0 = exp2f(s1[gg * 4 + 0]), r1 = exp2f(s1[gg * 4 + 1]);
          float r2 = exp2f(s1[gg * 4 + 2]), r3 = exp2f(s1[gg * 4 + 3]);
          sum += (r0 + r1) + (r2 + r3);
          pd2[gg].x = cvtpk(r0, r1); pd2[gg].y = cvtpk(r2, r3);
        }
#pragma unroll
        for (int c = 0; c < 2; ++c) {
          unsigned ax = pd2[2 * c].x, bx = pd2[2 * c + 1].x;
          unsigned ay = pd2[2 * c].y, by = pd2[2 * c + 1].y;
          plswap(ax, bx);
          plswap(ay, by);
          union { uint4 u; bf8 v; } pv2; pv2.u = (uint4){ax, ay, bx, by};
          o0 = MFMA32(vf[0][2 + c], pv2.v, o0);
          o1 = MFMA32(vf[1][2 + c], pv2.v, o1);
        }
      }
    };

    // K double-buffered, manual 2-step unroll over this wave's k-half
    if (kb < ke) {
      loadK(kfA, kb);
      int kt = kb;
      while (true) {
        if (kt + 1 < ke) loadK(kfB, kt + 1);
        step(kt, kfA);
        ++kt; if (kt >= ke) break;
        if (kt + 1 < ke) loadK(kfA, kt + 1);
        step(kt, kfB);
        ++kt; if (kt >= ke) break;
      }
    }

    // ---- combine the two k-halves (linear: fixed m=0) ----
    float lpart = sum + __shfl_xor(sum, 32);     // full row sum for this half

    if (kh == 0) {
#pragma unroll
      for (int gg = 0; gg < 4; ++gg) {
        f4 w0 = { o0[gg * 4 + 0], o0[gg * 4 + 1], o0[gg * 4 + 2], o0[gg * 4 + 3] };
        *(f4*)&osh[sub][lane][gg * 4] = w0;
        f4 w1 = { o1[gg * 4 + 0], o1[gg * 4 + 1], o1[gg * 4 + 2], o1[gg * 4 + 3] };
        *(f4*)&osh[sub][lane][16 + gg * 4] = w1;
      }
      lsh[sub][lane] = lpart;
    }
    __syncthreads();
    if (kh == 1) {
      float inv = 1.0f / (lpart + lsh[sub][lane]);
#pragma unroll
      for (int gg = 0; gg < 4; ++gg) {
        int d0 = gg * 8 + hl * 4;
        f4 a0 = *(f4*)&osh[sub][lane][gg * 4];
        f4 a1 = *(f4*)&osh[sub][lane][16 + gg * 4];
        us4 w0 = { f2b((o0[gg * 4 + 0] + a0[0]) * inv), f2b((o0[gg * 4 + 1] + a0[1]) * inv),
                   f2b((o0[gg * 4 + 2] + a0[2]) * inv), f2b((o0[gg * 4 + 3] + a0[3]) * inv) };
        *(us4*)&ctx[((size_t)(b * 2048 + q)) * 1024 + h * 64 + d0] = w0;
        us4 w1 = { f2b((o1[gg * 4 + 0] + a1[0]) * inv), f2b((o1[gg * 4 + 1] + a1[1]) * inv),
                   f2b((o1[gg * 4 + 2] + a1[2]) * inv), f2b((o1[gg * 4 + 3] + a1[3]) * inv) };
        *(us4*)&ctx[((size_t)(b * 2048 + q)) * 1024 + h * 64 + 32 + d0] = w1;
      }
    }
    // loop-top __syncthreads() protects osh/lsh before next item's writes
  }
}

// ---------------- output projection GEMM (fp32 out), 64x128 tiles, BK=64 ----------
__global__ __launch_bounds__(256) void gemm_out_kernel(
    const unsigned short* __restrict__ A,
    const unsigned short* __restrict__ Wt,
    const float* __restrict__ bias, float* __restrict__ out) {
  __shared__ unsigned short As[64 * 64];
  __shared__ unsigned short Bs[128 * 64];
  const int t = threadIdx.x;
  const int wave = t >> 6, lane = t & 63, quad = lane >> 4, l16 = lane & 15;
  const int wm = (wave & 1) * 32, wn = (wave >> 1) * 64;
  const int m0 = blockIdx.y * 64, n0 = blockIdx.x * 128;

  f4 acc[2][4];
#pragma unroll
  for (int mi = 0; mi < 2; ++mi)
#pragma unroll
    for (int ni = 0; ni < 4; ++ni) acc[mi][ni] = (f4)0.0f;

  for (int k0 = 0; k0 < 1024; k0 += 64) {
    __syncthreads();
    {
#pragma unroll
      for (int it = 0; it < 2; ++it) {
        int chunk = it * 256 + wave * 64 + lane;     // 0..511 -> A (64x64)
        int row = chunk >> 3, cc = chunk & 7;
        gload16(&A[(size_t)(m0 + row) * 1024 + k0 + (cc ^ (row & 7)) * 8],
                &As[(size_t)(it * 256 + wave * 64) * 8]);
      }
#pragma unroll
      for (int it = 0; it < 4; ++it) {
        int chunk = it * 256 + wave * 64 + lane;     // 0..1023 -> B (128x64)
        int row = chunk >> 3, cc = chunk & 7;
        gload16(&Wt[(size_t)(n0 + row) * 1024 + k0 + (cc ^ (row & 7)) * 8],
                &Bs[(size_t)(it * 256 + wave * 64) * 8]);
      }
    }
    __syncthreads();
#pragma unroll
    for (int kk = 0; kk < 2; ++kk) {
      const int sw = (kk * 4 + quad) ^ (l16 & 7);
      bf8 a[2], b[4];
#pragma unroll
      for (int mi = 0; mi < 2; ++mi)
        a[mi] = *(const bf8*)&As[(wm + mi * 16 + l16) * 64 + sw * 8];
#pragma unroll
      for (int ni = 0; ni < 4; ++ni)
        b[ni] = *(const bf8*)&Bs[(wn + ni * 16 + l16) * 64 + sw * 8];
#pragma unroll
      for (int mi = 0; mi < 2; ++mi)
#pragma unroll
        for (int ni = 0; ni < 4; ++ni)
          acc[mi][ni] = MFMA16(a[mi], b[ni], acc[mi][ni]);
    }
  }
#pragma unroll
  for (int ni = 0; ni < 4; ++ni) {
    int n = n0 + wn + ni * 16 + l16;
    float bv_ = bias[n];
#pragma unroll
    for (int mi = 0; mi < 2; ++mi) {
#pragma unroll
      for (int r = 0; r < 4; ++r) {
        int m = m0 + wm + mi * 16 + quad * 4 + r;
        out[(size_t)m * 1024 + n] = acc[mi][ni][r] + bv_;
      }
    }
  }
}

extern "C" void kernel_launch(void* const* d_in, const int* in_sizes, int n_in,
                              void* d_out, int out_size, void* d_ws, size_t ws_size,
                              hipStream_t stream) {
  const float* hidden = (const float*)d_in[0];
  const float* Wq = (const float*)d_in[1];
  const float* bq = (const float*)d_in[2];
  const float* Wk = (const float*)d_in[3];
  const float* bk = (const float*)d_in[4];
  const float* Wv = (const float*)d_in[5];
  const float* bv = (const float*)d_in[6];
  const float* Wd = (const float*)d_in[7];
  const float* bd = (const float*)d_in[8];
  float* out = (float*)d_out;

  char* ws = (char*)d_ws;
  unsigned short* Xb  = (unsigned short*)(ws);
  unsigned short* Wqt = (unsigned short*)(ws + ( 8ull << 20));
  unsigned short* Wkt = (unsigned short*)(ws + (10ull << 20));
  unsigned short* Wvt = (unsigned short*)(ws + (12ull << 20));
  unsigned short* Wdt = (unsigned short*)(ws + (14ull << 20));
  unsigned short* Qb  = (unsigned short*)(ws + (16ull << 20));
  unsigned short* Kb  = (unsigned short*)(ws + (24ull << 20));   // fragment layout
  unsigned short* Vb  = (unsigned short*)(ws + (32ull << 20));   // fragment layout
  unsigned short* Cb  = (unsigned short*)(ws + (40ull << 20));
  int*            cnt = (int*)(ws + (48ull << 20));              // flash work queue

  prep_kernel<<<dim3(32, 32, 5), 256, 0, stream>>>(
      Wq, Wk, Wv, Wd, Wqt, Wkt, Wvt, Wdt, hidden, Xb, cnt);
  gemm_qkv_kernel<<<dim3(8, 32, 3), 256, 0, stream>>>(
      Xb, Wqt, Wkt, Wvt, bq, bk, bv, Qb, Kb, Vb);
  flash_attn_kernel<<<768, 256, 0, stream>>>(Qb, Kb, Vb, Cb, cnt);
  gemm_out_kernel<<<dim3(8, 64), 256, 0, stream>>>(Cb, Wdt, bd, out);
}

// Round 9
// 192.807 us; speedup vs baseline: 1.0902x; 1.0902x over previous
//
#include <hip/hip_runtime.h>
#include <stdint.h>

typedef __bf16 bf8 __attribute__((ext_vector_type(8)));
typedef float f4 __attribute__((ext_vector_type(4)));
typedef float f16v __attribute__((ext_vector_type(16)));
typedef unsigned short us8 __attribute__((ext_vector_type(8)));
typedef unsigned short us4 __attribute__((ext_vector_type(4)));

#define MFMA16(a, b, c) __builtin_amdgcn_mfma_f32_16x16x32_bf16(a, b, c, 0, 0, 0)
#define MFMA32(a, b, c) __builtin_amdgcn_mfma_f32_32x32x16_bf16(a, b, c, 0, 0, 0)

__device__ __forceinline__ unsigned short f2b(float f) {
  union { float f; unsigned u; } x; x.f = f;
  unsigned u = x.u;
  u += 0x7fffu + ((u >> 16) & 1u);   // RNE
  return (unsigned short)(u >> 16);
}

// pack bf16(a) low, bf16(b) high — single instr (RNE)
__device__ __forceinline__ unsigned cvtpk(float a, float b) {
  unsigned r;
  asm("v_cvt_pk_bf16_f32 %0, %1, %2" : "=v"(r) : "v"(a), "v"(b));
  return r;
}

// v_permlane32_swap_b32: a' = {a.lo32lanes, b.lo32lanes}, b' = {a.hi, b.hi}
__device__ __forceinline__ void plswap(unsigned &a, unsigned &b) {
  asm("v_permlane32_swap_b32 %0, %1" : "+v"(a), "+v"(b));
}

// async global->LDS 16B per lane; lds dest = wave-uniform base + lane*16
__device__ __forceinline__ void gload16(const void* g, void* l) {
  __builtin_amdgcn_global_load_lds(
      (const __attribute__((address_space(1))) void*)g,
      (__attribute__((address_space(3))) void*)l, 16, 0, 0);
}

// ---- fused: fp32 W[k][n] -> bf16 Wt[n][k] (z<4) + hidden fp32->bf16 (z==4) ----
__global__ __launch_bounds__(256) void prep_kernel(
    const float* __restrict__ W0, const float* __restrict__ W1,
    const float* __restrict__ W2, const float* __restrict__ W3,
    unsigned short* __restrict__ T0, unsigned short* __restrict__ T1,
    unsigned short* __restrict__ T2, unsigned short* __restrict__ T3,
    const float* __restrict__ hid, unsigned short* __restrict__ hb) {
  if (blockIdx.z == 4) {
    int bi = blockIdx.x + 32 * blockIdx.y;        // 0..1023
#pragma unroll
    for (int k = 0; k < 4; ++k) {
      int i = bi * 1024 + k * 256 + threadIdx.x;
      float4 v = ((const float4*)hid)[i];
      us4 r = { f2b(v.x), f2b(v.y), f2b(v.z), f2b(v.w) };
      *(us4*)(hb + (size_t)i * 4) = r;
    }
    return;
  }
  const float* W; unsigned short* Wt;
  if (blockIdx.z == 0)      { W = W0; Wt = T0; }
  else if (blockIdx.z == 1) { W = W1; Wt = T1; }
  else if (blockIdx.z == 2) { W = W2; Wt = T2; }
  else                      { W = W3; Wt = T3; }
  __shared__ float tile[32][33];
  int tx = threadIdx.x & 31, ty = threadIdx.x >> 5;   // 32 x 8
  int kb = blockIdx.x * 32, nb = blockIdx.y * 32;
#pragma unroll
  for (int j = 0; j < 32; j += 8)
    tile[ty + j][tx] = W[(size_t)(kb + ty + j) * 1024 + nb + tx];
  __syncthreads();
#pragma unroll
  for (int j = 0; j < 32; j += 8)
    Wt[(size_t)(nb + ty + j) * 1024 + kb + tx] = f2b(tile[tx][ty + j]);
}

// ---------------- QKV projection GEMM (+ fused RoPE for Q,K) ----------------
// BK=64, both-sides chunk XOR swizzle (R6). Round-9: XCD-chunked block swizzle
// (T1) — consecutive dispatch ids round-robin across the 8 XCD L2s, so without
// remapping EVERY XCD fetches EVERY 256KB A-stripe (~8x redundant L3 traffic,
// the same mechanism that cost flash 20us in R8). Bijective remap gives each
// XCD a contiguous band of 4 m-stripes: per-XCD L2 footprint ~1MB A + Wt
// panels. Outputs bit-identical (pure index permutation).
// Q: bf16 (bh,s,d) row-major, pre-scaled by 0.125*log2(e).
// K: bf16 FRAGMENT-READY; V: bf16 FRAGMENT-READY (see flash kernel).
__global__ __launch_bounds__(256) void gemm_qkv_kernel(
    const unsigned short* __restrict__ X,
    const unsigned short* __restrict__ Wqt, const unsigned short* __restrict__ Wkt,
    const unsigned short* __restrict__ Wvt,
    const float* __restrict__ bq, const float* __restrict__ bk,
    const float* __restrict__ bv,
    unsigned short* __restrict__ Qo, unsigned short* __restrict__ Ko,
    unsigned short* __restrict__ Vo) {
  const unsigned short* Wt; const float* bias; unsigned short* out;
  if (blockIdx.z == 0)      { Wt = Wqt; bias = bq; out = Qo; }
  else if (blockIdx.z == 1) { Wt = Wkt; bias = bk; out = Ko; }
  else                      { Wt = Wvt; bias = bv; out = Vo; }

  __shared__ unsigned short As[128 * 64];
  __shared__ unsigned short Bs[128 * 64];
  const int t = threadIdx.x;
  const int wave = t >> 6, lane = t & 63, quad = lane >> 4, l16 = lane & 15;
  const int wm = (wave >> 1) * 64, wn = (wave & 1) * 64;
  // XCD-chunked swizzle: L = dispatch order within z-slice; xcd = L&7.
  // XCD k owns m-stripes [4k, 4k+4) x all 8 n-tiles.
  const int L = blockIdx.x + 8 * blockIdx.y;      // 0..255
  const int xcd = L & 7, w = L >> 3;              // w 0..31
  const int m0 = (xcd * 4 + (w >> 3)) * 128;
  const int n0 = (w & 7) * 128;

  f4 acc[4][4];
#pragma unroll
  for (int mi = 0; mi < 4; ++mi)
#pragma unroll
    for (int ni = 0; ni < 4; ++ni) acc[mi][ni] = (f4)0.0f;

  for (int k0 = 0; k0 < 1024; k0 += 64) {
    __syncthreads();
#pragma unroll
    for (int it = 0; it < 4; ++it) {
      int chunk = it * 256 + wave * 64 + lane;      // 0..1023 (128 rows x 8 chunks)
      int row = chunk >> 3, cc = chunk & 7;
      int csw = cc ^ (row & 7);                     // pre-swizzled global source
      gload16(&X[(size_t)(m0 + row) * 1024 + k0 + csw * 8],
              &As[(size_t)(it * 256 + wave * 64) * 8]);
      gload16(&Wt[(size_t)(n0 + row) * 1024 + k0 + csw * 8],
              &Bs[(size_t)(it * 256 + wave * 64) * 8]);
    }
    __syncthreads();
#pragma unroll
    for (int kk = 0; kk < 2; ++kk) {
      const int sw = (kk * 4 + quad) ^ (l16 & 7);   // swizzled read slot
      bf8 a[4], b[4];
#pragma unroll
      for (int mi = 0; mi < 4; ++mi)
        a[mi] = *(const bf8*)&As[(wm + mi * 16 + l16) * 64 + sw * 8];
#pragma unroll
      for (int ni = 0; ni < 4; ++ni)
        b[ni] = *(const bf8*)&Bs[(wn + ni * 16 + l16) * 64 + sw * 8];
#pragma unroll
      for (int mi = 0; mi < 4; ++mi)
#pragma unroll
        for (int ni = 0; ni < 4; ++ni)
          acc[mi][ni] = MFMA16(a[mi], b[ni], acc[mi][ni]);
    }
  }

  float biasv[4];
#pragma unroll
  for (int ni = 0; ni < 4; ++ni) biasv[ni] = bias[n0 + wn + ni * 16 + l16];

  if (blockIdx.z < 2) {
    const float kr = 13.287712379549449f / 32.0f;   // log2(10000)/32
    const float f0 = exp2f(-(float)l16 * kr);
    const float f1 = exp2f(-(float)(l16 + 16) * kr);
    const float qs = (blockIdx.z == 0) ? 0.18033688011112042f : 1.0f;
#pragma unroll
    for (int mi = 0; mi < 4; ++mi) {
#pragma unroll
      for (int r = 0; r < 4; ++r) {
        int m = m0 + wm + mi * 16 + quad * 4 + r;
        float s = (float)(m & 2047);
        float s0, c0, s1, c1;
        __sincosf(s * f0, &s0, &c0);
        __sincosf(s * f1, &s1, &c1);
        float v0 = acc[mi][0][r] + biasv[0];
        float v1 = acc[mi][1][r] + biasv[1];
        acc[mi][0][r] = (v0 * c0 - v1 * s0) * qs;
        acc[mi][1][r] = (v1 * c1 - v0 * s1) * qs;
        acc[mi][2][r] = (acc[mi][2][r] + biasv[2]) * qs;
        acc[mi][3][r] = (acc[mi][3][r] + biasv[3]) * qs;
      }
    }
    if (blockIdx.z == 0) {
      // Q: row-major (bh, s, d)
#pragma unroll
      for (int ni = 0; ni < 4; ++ni) {
        int n = n0 + wn + ni * 16 + l16;
        int h = n >> 6, d = n & 63;
#pragma unroll
        for (int mi = 0; mi < 4; ++mi) {
#pragma unroll
          for (int r = 0; r < 4; ++r) {
            int m = m0 + wm + mi * 16 + quad * 4 + r;
            int b_ = m >> 11, s = m & 2047;
            out[(size_t)(((b_ << 4) | h) * 2048 + s) * 64 + d] = f2b(acc[mi][ni][r]);
          }
        }
      }
    } else {
      // K: fragment-ready layout
#pragma unroll
      for (int ni = 0; ni < 4; ++ni) {
        int n = n0 + wn + ni * 16 + l16;
        int h = n >> 6, d = n & 63;
        int cpart = (d >> 4) * 512 + ((d >> 3) & 1) * 256 + (d & 7);
#pragma unroll
        for (int mi = 0; mi < 4; ++mi) {
#pragma unroll
          for (int r = 0; r < 4; ++r) {
            int m = m0 + wm + mi * 16 + quad * 4 + r;
            int b_ = m >> 11, s = m & 2047;
            size_t off = (size_t)((b_ << 4) | h) * 131072
                       + (size_t)(s >> 5) * 2048 + (s & 31) * 8 + cpart;
            out[off] = f2b(acc[mi][ni][r]);
          }
        }
      }
    }
  } else {
    // V: fragment-ready layout (us4 = 4 consecutive s at fixed d)
#pragma unroll
    for (int ni = 0; ni < 4; ++ni) {
      int n = n0 + wn + ni * 16 + l16;
      int h = n >> 6, d = n & 63;
      int dpart = ((d >> 5) & 1) * 2048 + (d & 31) * 8;
#pragma unroll
      for (int mi = 0; mi < 4; ++mi) {
        int m = m0 + wm + mi * 16 + quad * 4;
        int b_ = m >> 11, s = m & 2047;
        us4 w = { f2b(acc[mi][ni][0] + biasv[ni]), f2b(acc[mi][ni][1] + biasv[ni]),
                  f2b(acc[mi][ni][2] + biasv[ni]), f2b(acc[mi][ni][3] + biasv[ni]) };
        size_t off = (size_t)((b_ << 4) | h) * 131072
                   + (size_t)(s >> 6) * 4096 + ((s >> 4) & 3) * 512
                   + ((s >> 3) & 1) * 256 + dpart + (s & 7);
        *(us4*)&out[off] = w;
      }
    }
  }
}

// ------------- causal flash attention, SPLIT-K (R7 structure, best: 51.8us) ----
// Static grid, static bh=id&31 mapping (4 bh per XCD -> K/V L2-resident; R8's
// dynamic queue broke this: FETCH 12->97MB, +21us. Do not re-add).
// R8 also falsified the drain theory (persistent blocks: occupancy unchanged)
// -> ~52us is this chain's structural floor.
__global__ __launch_bounds__(256) void flash_attn_kernel(
    const unsigned short* __restrict__ Q, const unsigned short* __restrict__ K,
    const unsigned short* __restrict__ Vt, unsigned short* __restrict__ ctx) {
  __shared__ __align__(16) float osh[2][64][36];   // stride 36: 16B-aligned rows
  __shared__ float lsh[2][64];
  const int t = threadIdx.x;
  const int lane = t & 63;
  const int wave = t >> 6, l32 = lane & 31, hl = lane >> 5;
  const int sub = wave >> 1;                     // q-subtile within 64-row tile
  const int kh  = wave & 1;                      // k-half

  const int id = blockIdx.x;                     // 0..1023
  const int bh = id & 31;
  const int j = id >> 5;                         // 0..31
  const int qt = (j & 16) ? (31 - (j & 15)) : (j & 15);   // balanced map
  const int b = bh >> 4, h = bh & 15;

  const unsigned short* Qh = Q + (size_t)bh * 131072;
  const unsigned short* Kh = K + (size_t)bh * 131072;
  const unsigned short* Vh = Vt + (size_t)bh * 131072;

  const int wrow0 = qt * 64 + sub * 32;
  const int q = wrow0 + l32;                     // lane's q-column

  // Q as B-operand: B[k=d][n=q]; chunk c covers d = c*16 + hl*8 + j
  bf8 qb[4];
#pragma unroll
  for (int c = 0; c < 4; ++c)
    qb[c] = *(const bf8*)&Qh[(size_t)q * 64 + c * 16 + hl * 8];

  f16v o0 = (f16v)0.0f, o1 = (f16v)0.0f;         // O^T: d 0..31, 32..63
  float sum = 0.0f;                              // per-lane partial l

  bf8 kfA[2][4], kfB[2][4];
  const int nk = qt + 1;                         // total 64-wide k-steps
  const int kb = kh ? (nk >> 1) : 0;             // this wave's half
  const int ke = kh ? nk : (nk >> 1);

  // fragment-ready K: chunk offset (ushorts) = kt*4096 + mt*2048 + c*512 + lane*8
  auto loadK = [&](bf8 (&kf)[2][4], int kt) {
    const unsigned short* p = Kh + (size_t)kt * 4096 + lane * 8;
#pragma unroll
    for (int mt = 0; mt < 2; ++mt)
#pragma unroll
      for (int c = 0; c < 4; ++c)
        kf[mt][c] = *(const bf8*)&p[mt * 2048 + c * 512];
  };

  auto step = [&](int kt, bf8 (&kf)[2][4]) {
    const int k0 = kt * 64;

    // S^T = K Q^T : two 32x32 tiles over kk (reg gg*4+i <-> kk=gg*8+hl*4+i)
    f16v s0 = (f16v)0.0f, s1 = (f16v)0.0f;
#pragma unroll
    for (int c = 0; c < 4; ++c) {
      s0 = MFMA32(kf[0][c], qb[c], s0);
      s1 = MFMA32(kf[1][c], qb[c], s1);
    }
    __builtin_amdgcn_sched_barrier(0);   // pin V loads BELOW QK^T (VGPR peak)

    // fragment-ready V: kt*4096 + dt*2048 + c*512 + lane*8.
    // Issued here; latency covered by softmax-s0 below.
    const unsigned short* pv = Vh + (size_t)kt * 4096 + lane * 8;
    bf8 vf[2][4];
#pragma unroll
    for (int c = 0; c < 4; ++c)
#pragma unroll
      for (int dt = 0; dt < 2; ++dt)
        vf[dt][c] = *(const bf8*)&pv[dt * 2048 + c * 512];

    // causal mask: provably only the last tile of the full range
    if (kt == nk - 1) {
#pragma unroll
      for (int gg = 0; gg < 4; ++gg)
#pragma unroll
        for (int i = 0; i < 4; ++i) {
          int kk = k0 + gg * 8 + hl * 4 + i;
          if (kk > q) s0[gg * 4 + i] = -3e38f;
          if (kk + 32 > q) s1[gg * 4 + i] = -3e38f;
        }
    }

    // ---- first half: s0 -> fragments c=0,1 -> PV ----
    {
      uint2 pd2[4];
#pragma unroll
      for (int gg = 0; gg < 4; ++gg) {
        float p0 = exp2f(s0[gg * 4 + 0]), p1 = exp2f(s0[gg * 4 + 1]);
        float p2 = exp2f(s0[gg * 4 + 2]), p3 = exp2f(s0[gg * 4 + 3]);
        sum += (p0 + p1) + (p2 + p3);
        pd2[gg].x = cvtpk(p0, p1); pd2[gg].y = cvtpk(p2, p3);
      }
#pragma unroll
      for (int c = 0; c < 2; ++c) {
        unsigned ax = pd2[2 * c].x, bx = pd2[2 * c + 1].x;
        unsigned ay = pd2[2 * c].y, by = pd2[2 * c + 1].y;
        plswap(ax, bx);
        plswap(ay, by);
        union { uint4 u; bf8 v; } pv2; pv2.u = (uint4){ax, ay, bx, by};
        o0 = MFMA32(vf[0][c], pv2.v, o0);
        o1 = MFMA32(vf[1][c], pv2.v, o1);
      }
    }
    // ---- second half: s1 -> fragments c=2,3 -> PV ----
    {
      uint2 pd2[4];
#pragma unroll
      for (int gg = 0; gg < 4; ++gg) {
        float r0 = exp2f(s1[gg * 4 + 0]), r1 = exp2f(s1[gg * 4 + 1]);
        float r2 = exp2f(s1[gg * 4 + 2]), r3 = exp2f(s1[gg * 4 + 3]);
        sum += (r0 + r1) + (r2 + r3);
        pd2[gg].x = cvtpk(r0, r1); pd2[gg].y = cvtpk(r2, r3);
      }
#pragma unroll
      for (int c = 0; c < 2; ++c) {
        unsigned ax = pd2[2 * c].x, bx = pd2[2 * c + 1].x;
        unsigned ay = pd2[2 * c].y, by = pd2[2 * c + 1].y;
        plswap(ax, bx);
        plswap(ay, by);
        union { uint4 u; bf8 v; } pv2; pv2.u = (uint4){ax, ay, bx, by};
        o0 = MFMA32(vf[0][2 + c], pv2.v, o0);
        o1 = MFMA32(vf[1][2 + c], pv2.v, o1);
      }
    }
  };

  // K double-buffered, manual 2-step unroll over this wave's k-half
  if (kb < ke) {
    loadK(kfA, kb);
    int kt = kb;
    while (true) {
      if (kt + 1 < ke) loadK(kfB, kt + 1);
      step(kt, kfA);
      ++kt; if (kt >= ke) break;
      if (kt + 1 < ke) loadK(kfA, kt + 1);
      step(kt, kfB);
      ++kt; if (kt >= ke) break;
    }
  }

  // ---- combine the two k-halves (linear: fixed m=0) ----
  float lpart = sum + __shfl_xor(sum, 32);       // full row sum for this half

  if (kh == 0) {
#pragma unroll
    for (int gg = 0; gg < 4; ++gg) {
      f4 w0 = { o0[gg * 4 + 0], o0[gg * 4 + 1], o0[gg * 4 + 2], o0[gg * 4 + 3] };
      *(f4*)&osh[sub][lane][gg * 4] = w0;
      f4 w1 = { o1[gg * 4 + 0], o1[gg * 4 + 1], o1[gg * 4 + 2], o1[gg * 4 + 3] };
      *(f4*)&osh[sub][lane][16 + gg * 4] = w1;
    }
    lsh[sub][lane] = lpart;
  }
  __syncthreads();
  if (kh == 1) {
    float inv = 1.0f / (lpart + lsh[sub][lane]);
#pragma unroll
    for (int gg = 0; gg < 4; ++gg) {
      int d0 = gg * 8 + hl * 4;
      f4 a0 = *(f4*)&osh[sub][lane][gg * 4];
      f4 a1 = *(f4*)&osh[sub][lane][16 + gg * 4];
      us4 w0 = { f2b((o0[gg * 4 + 0] + a0[0]) * inv), f2b((o0[gg * 4 + 1] + a0[1]) * inv),
                 f2b((o0[gg * 4 + 2] + a0[2]) * inv), f2b((o0[gg * 4 + 3] + a0[3]) * inv) };
      *(us4*)&ctx[((size_t)(b * 2048 + q)) * 1024 + h * 64 + d0] = w0;
      us4 w1 = { f2b((o1[gg * 4 + 0] + a1[0]) * inv), f2b((o1[gg * 4 + 1] + a1[1]) * inv),
                 f2b((o1[gg * 4 + 2] + a1[2]) * inv), f2b((o1[gg * 4 + 3] + a1[3]) * inv) };
      *(us4*)&ctx[((size_t)(b * 2048 + q)) * 1024 + h * 64 + 32 + d0] = w1;
    }
  }
}

// ---------------- output projection GEMM (fp32 out), 64x128 tiles, BK=64 ----------
// Round-9: same XCD-chunked swizzle as gemm_qkv (each XCD owns 8 m-stripes).
__global__ __launch_bounds__(256) void gemm_out_kernel(
    const unsigned short* __restrict__ A,
    const unsigned short* __restrict__ Wt,
    const float* __restrict__ bias, float* __restrict__ out) {
  __shared__ unsigned short As[64 * 64];
  __shared__ unsigned short Bs[128 * 64];
  const int t = threadIdx.x;
  const int wave = t >> 6, lane = t & 63, quad = lane >> 4, l16 = lane & 15;
  const int wm = (wave & 1) * 32, wn = (wave >> 1) * 64;
  const int L = blockIdx.x + 8 * blockIdx.y;      // 0..511 dispatch order
  const int xcd = L & 7, w = L >> 3;              // w 0..63
  const int m0 = (xcd * 8 + (w >> 3)) * 64;
  const int n0 = (w & 7) * 128;

  f4 acc[2][4];
#pragma unroll
  for (int mi = 0; mi < 2; ++mi)
#pragma unroll
    for (int ni = 0; ni < 4; ++ni) acc[mi][ni] = (f4)0.0f;

  for (int k0 = 0; k0 < 1024; k0 += 64) {
    __syncthreads();
    {
#pragma unroll
      for (int it = 0; it < 2; ++it) {
        int chunk = it * 256 + wave * 64 + lane;     // 0..511 -> A (64x64)
        int row = chunk >> 3, cc = chunk & 7;
        gload16(&A[(size_t)(m0 + row) * 1024 + k0 + (cc ^ (row & 7)) * 8],
                &As[(size_t)(it * 256 + wave * 64) * 8]);
      }
#pragma unroll
      for (int it = 0; it < 4; ++it) {
        int chunk = it * 256 + wave * 64 + lane;     // 0..1023 -> B (128x64)
        int row = chunk >> 3, cc = chunk & 7;
        gload16(&Wt[(size_t)(n0 + row) * 1024 + k0 + (cc ^ (row & 7)) * 8],
                &Bs[(size_t)(it * 256 + wave * 64) * 8]);
      }
    }
    __syncthreads();
#pragma unroll
    for (int kk = 0; kk < 2; ++kk) {
      const int sw = (kk * 4 + quad) ^ (l16 & 7);
      bf8 a[2], b[4];
#pragma unroll
      for (int mi = 0; mi < 2; ++mi)
        a[mi] = *(const bf8*)&As[(wm + mi * 16 + l16) * 64 + sw * 8];
#pragma unroll
      for (int ni = 0; ni < 4; ++ni)
        b[ni] = *(const bf8*)&Bs[(wn + ni * 16 + l16) * 64 + sw * 8];
#pragma unroll
      for (int mi = 0; mi < 2; ++mi)
#pragma unroll
        for (int ni = 0; ni < 4; ++ni)
          acc[mi][ni] = MFMA16(a[mi], b[ni], acc[mi][ni]);
    }
  }
#pragma unroll
  for (int ni = 0; ni < 4; ++ni) {
    int n = n0 + wn + ni * 16 + l16;
    float bv_ = bias[n];
#pragma unroll
    for (int mi = 0; mi < 2; ++mi) {
#pragma unroll
      for (int r = 0; r < 4; ++r) {
        int m = m0 + wm + mi * 16 + quad * 4 + r;
        out[(size_t)m * 1024 + n] = acc[mi][ni][r] + bv_;
      }
    }
  }
}

extern "C" void kernel_launch(void* const* d_in, const int* in_sizes, int n_in,
                              void* d_out, int out_size, void* d_ws, size_t ws_size,
                              hipStream_t stream) {
  const float* hidden = (const float*)d_in[0];
  const float* Wq = (const float*)d_in[1];
  const float* bq = (const float*)d_in[2];
  const float* Wk = (const float*)d_in[3];
  const float* bk = (const float*)d_in[4];
  const float* Wv = (const float*)d_in[5];
  const float* bv = (const float*)d_in[6];
  const float* Wd = (const float*)d_in[7];
  const float* bd = (const float*)d_in[8];
  float* out = (float*)d_out;

  char* ws = (char*)d_ws;
  unsigned short* Xb  = (unsigned short*)(ws);
  unsigned short* Wqt = (unsigned short*)(ws + ( 8ull << 20));
  unsigned short* Wkt = (unsigned short*)(ws + (10ull << 20));
  unsigned short* Wvt = (unsigned short*)(ws + (12ull << 20));
  unsigned short* Wdt = (unsigned short*)(ws + (14ull << 20));
  unsigned short* Qb  = (unsigned short*)(ws + (16ull << 20));
  unsigned short* Kb  = (unsigned short*)(ws + (24ull << 20));   // fragment layout
  unsigned short* Vb  = (unsigned short*)(ws + (32ull << 20));   // fragment layout
  unsigned short* Cb  = (unsigned short*)(ws + (40ull << 20));

  prep_kernel<<<dim3(32, 32, 5), 256, 0, stream>>>(
      Wq, Wk, Wv, Wd, Wqt, Wkt, Wvt, Wdt, hidden, Xb);
  gemm_qkv_kernel<<<dim3(8, 32, 3), 256, 0, stream>>>(
      Xb, Wqt, Wkt, Wvt, bq, bk, bv, Qb, Kb, Vb);
  flash_attn_kernel<<<1024, 256, 0, stream>>>(Qb, Kb, Vb, Cb);
  gemm_out_kernel<<<dim3(8, 64), 256, 0, stream>>>(Cb, Wdt, bd, out);
}